// Round 2
// baseline (242.758 us; speedup 1.0000x reference)
//
#include <hip/hip_runtime.h>

// Problem constants (B,C,H,W fixed by the reference setup)
#define B_   8
#define C_   10
#define H_   128
#define W_   128
#define HWSZ (H_ * W_)    // 16384
#define CHW  (C_ * HWSZ)  // 163840

#define TS   16           // spatial tile (16x16 outputs per block)
#define HL   18           // halo extent (TS + 2)
#define HST  19           // padded LDS row stride (odd -> spreads banks)
#define HSZ  (HL * HL)    // 324 halo pixels
#define NTHREADS 128      // 2 horizontal pixels per thread

__device__ __forceinline__ float sigm(float x)  { return 1.0f / (1.0f + __expf(-x)); }
__device__ __forceinline__ float tanh_(float x) { return 1.0f - 2.0f / (__expf(2.0f * x) + 1.0f); }

__global__ __launch_bounds__(NTHREADS) void fused_graph_kernel(
    const float* __restrict__ f_g,
    const float* __restrict__ h0_g,
    const float* __restrict__ h1_g,
    const float* __restrict__ attw_g,
    const float* __restrict__ attb_g,
    const float* __restrict__ relw_g,
    const float* __restrict__ gamma_g,
    const float* __restrict__ beta_g,
    const float* __restrict__ mean_g,
    const float* __restrict__ var_g,
    const float* __restrict__ gw_g,
    const float* __restrict__ gb_g,
    const float* __restrict__ cw_g,
    const float* __restrict__ cb_g,
    float* __restrict__ out_f,
    float* __restrict__ out_att)
{
    // LDS: input halo tiles (fp32) + re-laid-out weights. ~54 KB total.
    __shared__ float sF [C_][HL * HST];
    __shared__ float sA0[C_][HL * HST];
    __shared__ float sA1[C_][HL * HST];
    __shared__ float sAtt[HL * HST];
    __shared__ float sWf[9][10][12];   // [tap][ci][c_out] (c padded 10->12)
    __shared__ float sWa[9][10][12];
    __shared__ float sGW[20][20];      // [in][out]
    __shared__ float sCW[20][12];      // [in][c_out]
    __shared__ float sGB[20], sCB[10], sSc[10], sBi[10];

    const int tid = threadIdx.x;
    const int bx = blockIdx.x, by = blockIdx.y, b = blockIdx.z;

    // ---- weight staging (global -> LDS, transposed for broadcast reads) ----
    for (int i = tid; i < 900; i += NTHREADS) {
        const int tap = i / 100, r = i - tap * 100, ci = r / 10, c = r - ci * 10;
        // rel_w layout: [c_out=10][ci=20][ky][kx]; ci<10 multiplies f, ci>=10 multiplies child*att
        sWf[tap][ci][c] = relw_g[(c * 20 + ci) * 9 + tap];
        sWa[tap][ci][c] = relw_g[(c * 20 + 10 + ci) * 9 + tap];
    }
    for (int i = tid; i < 400; i += NTHREADS) {
        const int in_c = i / 20, o = i - in_c * 20;
        sGW[in_c][o] = gw_g[o * 20 + in_c];
    }
    for (int i = tid; i < 200; i += NTHREADS) {
        const int in_c = i / 10, c = i - in_c * 10;
        sCW[in_c][c] = cw_g[c * 20 + in_c];
    }
    if (tid < 20) sGB[tid] = gb_g[tid];
    if (tid < 10) {
        sCB[tid] = cb_g[tid];
        const float sc = gamma_g[tid] * rsqrtf(var_g[tid] + 1e-5f);
        sSc[tid] = sc;                                     // gamma/sqrt(var+eps)
        sBi[tid] = beta_g[tid] - mean_g[tid] * sc;
    }

    // attention 1x1 weights: wave-uniform, keep in registers
    float aw[20];
    #pragma unroll
    for (int i = 0; i < 20; i++) aw[i] = attw_g[i];
    const float ab = attb_g[0];

    // ---- input halo staging; compute att per halo pixel once ----
    const int gy0 = by * TS - 1, gx0 = bx * TS - 1;
    for (int p = tid; p < HSZ; p += NTHREADS) {
        const int hy = p / HL, hx = p - hy * HL;
        const int gy = gy0 + hy, gx = gx0 + hx;
        const int q = hy * HST + hx;
        if (gy >= 0 && gy < H_ && gx >= 0 && gx < W_) {
            const int base = b * CHW + gy * W_ + gx;
            float h0v[10], h1v[10];
            float acc = ab;
            #pragma unroll
            for (int ci = 0; ci < 10; ci++) {
                h0v[ci] = h0_g[base + ci * HWSZ];
                h1v[ci] = h1_g[base + ci * HWSZ];
                acc += aw[ci] * h0v[ci] + aw[10 + ci] * h1v[ci];
            }
            const float att = sigm(acc);
            sAtt[q] = att;
            #pragma unroll
            for (int ci = 0; ci < 10; ci++) {
                sF [ci][q] = f_g[base + ci * HWSZ];
                sA0[ci][q] = h0v[ci] * att;
                sA1[ci][q] = h1v[ci] * att;
            }
        } else {  // zero padding (conv pad=1)
            sAtt[q] = 0.0f;
            #pragma unroll
            for (int ci = 0; ci < 10; ci++) { sF[ci][q] = 0.0f; sA0[ci][q] = 0.0f; sA1[ci][q] = 0.0f; }
        }
    }
    __syncthreads();

    // ---- 3x3 conv, f-part shared between both relations; 2 pixels/thread ----
    const int ly = tid >> 3, lxp = tid & 7;
    const int hc = (ly + 1) * HST + (2 * lxp + 1);  // halo index of pixel 0

    float accf[2][10], acc0[2][10], acc1[2][10];
    #pragma unroll
    for (int c = 0; c < 10; c++) {
        accf[0][c] = 0.f; accf[1][c] = 0.f;
        acc0[0][c] = 0.f; acc0[1][c] = 0.f;
        acc1[0][c] = 0.f; acc1[1][c] = 0.f;
    }

    #pragma unroll 1  // keep 9-tap loop rolled: body is ~700 instrs, fits icache
    for (int tap = 0; tap < 9; tap++) {
        const int dy = tap / 3 - 1, dx = tap - (tap / 3) * 3 - 1;
        const int hi = hc + dy * HST + dx;
        #pragma unroll
        for (int ci = 0; ci < 10; ci++) {
            const float f0 = sF [ci][hi], f1 = sF [ci][hi + 1];
            const float p0 = sA0[ci][hi], p1 = sA0[ci][hi + 1];
            const float q0 = sA1[ci][hi], q1 = sA1[ci][hi + 1];
            #pragma unroll
            for (int c = 0; c < 10; c++) {
                const float wfv = sWf[tap][ci][c];
                const float wav = sWa[tap][ci][c];
                accf[0][c] += wfv * f0; accf[1][c] += wfv * f1;
                acc0[0][c] += wav * p0; acc0[1][c] += wav * p1;
                acc1[0][c] += wav * q0; acc1[1][c] += wav * q1;
            }
        }
    }

    // ---- BN + ReLU + sum; ConvGRU (1x1) per pixel ----
    const int gy = by * TS + ly, gx = bx * TS + 2 * lxp;
    float fnew[2][10];
    #pragma unroll
    for (int px = 0; px < 2; px++) {
        float ch[10], fc[10];
        #pragma unroll
        for (int c = 0; c < 10; c++) {
            const float y0 = (accf[px][c] + acc0[px][c]) * sSc[c] + sBi[c];
            const float y1 = (accf[px][c] + acc1[px][c]) * sSc[c] + sBi[c];
            ch[c] = fmaxf(y0, 0.f) + fmaxf(y1, 0.f);
            fc[c] = sF[c][hc + px];
        }
        float g[20];
        #pragma unroll
        for (int o = 0; o < 20; o++) g[o] = sGB[o];
        #pragma unroll
        for (int i = 0; i < 10; i++) {
            #pragma unroll
            for (int o = 0; o < 20; o++)
                g[o] += ch[i] * sGW[i][o] + fc[i] * sGW[10 + i][o];
        }
        float cd[10];
        #pragma unroll
        for (int c = 0; c < 10; c++) cd[c] = sCB[c];
        #pragma unroll
        for (int i = 0; i < 10; i++) {
            const float rf = sigm(g[i]) * fc[i];   // reset * f
            #pragma unroll
            for (int c = 0; c < 10; c++)
                cd[c] += ch[i] * sCW[i][c] + rf * sCW[10 + i][c];
        }
        #pragma unroll
        for (int c = 0; c < 10; c++) {
            const float u = sigm(g[10 + c]);       // update gate
            fnew[px][c] = (1.f - u) * fc[c] + u * tanh_(cd[c]);
        }
    }

    // ---- packed float2 stores (gx is even -> 8B aligned) ----
    #pragma unroll
    for (int c = 0; c < 10; c++) {
        float2 v = make_float2(fnew[0][c], fnew[1][c]);
        *reinterpret_cast<float2*>(&out_f[((b * C_ + c) * H_ + gy) * W_ + gx]) = v;
    }
    {
        float2 v = make_float2(sAtt[hc], sAtt[hc + 1]);
        *reinterpret_cast<float2*>(&out_att[(b * H_ + gy) * W_ + gx]) = v;
    }
}

extern "C" void kernel_launch(void* const* d_in, const int* in_sizes, int n_in,
                              void* d_out, int out_size, void* d_ws, size_t ws_size,
                              hipStream_t stream) {
    (void)in_sizes; (void)n_in; (void)d_ws; (void)ws_size; (void)out_size;
    const float* f   = (const float*)d_in[0];
    const float* h0  = (const float*)d_in[1];
    const float* h1  = (const float*)d_in[2];
    // d_in[3] = p_nodes, d_in[4] = xf: unused by the reference -> never read
    const float* aw  = (const float*)d_in[5];
    const float* ab  = (const float*)d_in[6];
    const float* rw  = (const float*)d_in[7];
    const float* gam = (const float*)d_in[8];
    const float* bet = (const float*)d_in[9];
    const float* mea = (const float*)d_in[10];
    const float* var = (const float*)d_in[11];
    const float* gw  = (const float*)d_in[12];
    const float* gb  = (const float*)d_in[13];
    const float* cw  = (const float*)d_in[14];
    const float* cb  = (const float*)d_in[15];

    float* out_f   = (float*)d_out;
    float* out_att = out_f + (B_ * C_ * H_ * W_);

    dim3 grid(W_ / TS, H_ / TS, B_);
    fused_graph_kernel<<<grid, dim3(NTHREADS), 0, stream>>>(
        f, h0, h1, aw, ab, rw, gam, bet, mea, var, gw, gb, cw, cb, out_f, out_att);
}

// Round 3
// 241.792 us; speedup vs baseline: 1.0040x; 1.0040x over previous
//
#include <hip/hip_runtime.h>

// Problem constants (B,C,H,W fixed by the reference setup)
#define B_   8
#define C_   10
#define H_   128
#define W_   128
#define HWSZ (H_ * W_)    // 16384
#define CHW  (C_ * HWSZ)  // 163840

#define TS   16           // spatial tile (16x16 outputs per block)
#define HL   18           // halo extent (TS + 2)
#define HST  19           // padded LDS row stride (odd -> spreads banks)
#define HSZ  (HL * HL)    // 324 halo pixels
#define NTHREADS 256      // 1 pixel per thread

// d_ws packed-weight layout (floats)
#define WOFF_W3 0         // [tap*10+ci]*20 : [0..9]=wf*sc (c), [10..19]=wa*sc (c)   (1800)
#define WOFF_BI 1800      // BN folded bias per c                                     (10)
#define WOFF_AW 1810      // att 1x1 weights                                          (20)
#define WOFF_AB 1830      // att bias                                                 (1)
#define WOFF_GW 1832      // gates W [in=20][out=20]                                  (400)
#define WOFF_GB 2232      // gates bias                                               (20)
#define WOFF_CW 2252      // cand W [in=20][c=10]                                     (200)
#define WOFF_CB 2452      // cand bias                                                (10)

__device__ __forceinline__ float sigm(float x)  { return 1.0f / (1.0f + __expf(-x)); }
__device__ __forceinline__ float tanh_(float x) { return 1.0f - 2.0f / (__expf(2.0f * x) + 1.0f); }

// ---- tiny prep kernel: fold BN into rel_w, transpose & pack all weights into d_ws ----
__global__ __launch_bounds__(256) void prep_kernel(
    const float* __restrict__ attw, const float* __restrict__ attb,
    const float* __restrict__ relw,
    const float* __restrict__ gamma, const float* __restrict__ beta,
    const float* __restrict__ mean,  const float* __restrict__ var,
    const float* __restrict__ gw, const float* __restrict__ gb,
    const float* __restrict__ cw, const float* __restrict__ cb,
    float* __restrict__ ws)
{
    const int tid = threadIdx.x;
    // rel_w: [c_out=10][cin=20][ky][kx]; cin<10 multiplies f, cin>=10 multiplies child*att
    for (int i = tid; i < 1800; i += 256) {
        const int g20 = i / 20, j = i - g20 * 20;        // g20 = tap*10 + ci
        const int tap = g20 / 10, ci = g20 - tap * 10;
        const int c   = (j < 10) ? j : j - 10;           // output channel
        const int cin = (j < 10) ? ci : 10 + ci;
        const float sc = gamma[c] * rsqrtf(var[c] + 1e-5f);
        ws[WOFF_W3 + i] = relw[(c * 20 + cin) * 9 + tap] * sc;
    }
    if (tid < 10) {
        const float sc = gamma[tid] * rsqrtf(var[tid] + 1e-5f);
        ws[WOFF_BI + tid] = beta[tid] - mean[tid] * sc;
        ws[WOFF_CB + tid] = cb[tid];
    }
    if (tid < 20) {
        ws[WOFF_AW + tid] = attw[tid];
        ws[WOFF_GB + tid] = gb[tid];
    }
    if (tid == 0) ws[WOFF_AB] = attb[0];
    for (int i = tid; i < 400; i += 256) {               // [in][out] transpose
        const int ic = i / 20, o = i - ic * 20;
        ws[WOFF_GW + i] = gw[o * 20 + ic];
    }
    for (int i = tid; i < 200; i += 256) {               // [in][c] transpose
        const int ic = i / 10, c = i - ic * 10;
        ws[WOFF_CW + i] = cw[c * 20 + ic];
    }
}

__global__ __launch_bounds__(NTHREADS) void fused_graph_kernel(
    const float* __restrict__ f_g,
    const float* __restrict__ h0_g,
    const float* __restrict__ h1_g,
    const float* __restrict__ ws,
    float* __restrict__ out_f,
    float* __restrict__ out_att)
{
    // LDS: halo tile, float4 per (channel, pixel): (f, h0*att, h1*att, att). ~54.7 KB.
    __shared__ float4 sIn[C_][HL * HST];

    const int tid = threadIdx.x;
    const int bx = blockIdx.x, by = blockIdx.y, b = blockIdx.z;

    // attention 1x1 weights: wave-uniform -> scalar loads, live in SGPRs
    float aw[20];
    #pragma unroll
    for (int i = 0; i < 20; i++) aw[i] = ws[WOFF_AW + i];
    const float ab = ws[WOFF_AB];

    // ---- input halo staging; compute att per halo pixel once ----
    const int gy0 = by * TS - 1, gx0 = bx * TS - 1;
    for (int p = tid; p < HSZ; p += NTHREADS) {
        const int hy = p / HL, hx = p - hy * HL;
        const int gy = gy0 + hy, gx = gx0 + hx;
        const int q = hy * HST + hx;
        if (gy >= 0 && gy < H_ && gx >= 0 && gx < W_) {
            const int base = b * CHW + gy * W_ + gx;
            float fv[10], h0v[10], h1v[10];
            float acc = ab;
            #pragma unroll
            for (int ci = 0; ci < 10; ci++) {
                fv[ci]  = f_g [base + ci * HWSZ];
                h0v[ci] = h0_g[base + ci * HWSZ];
                h1v[ci] = h1_g[base + ci * HWSZ];
                acc += aw[ci] * h0v[ci] + aw[10 + ci] * h1v[ci];
            }
            const float att = sigm(acc);
            #pragma unroll
            for (int ci = 0; ci < 10; ci++)
                sIn[ci][q] = make_float4(fv[ci], h0v[ci] * att, h1v[ci] * att, att);
        } else {  // zero padding (conv pad=1)
            #pragma unroll
            for (int ci = 0; ci < 10; ci++)
                sIn[ci][q] = make_float4(0.f, 0.f, 0.f, 0.f);
        }
    }
    __syncthreads();

    // ---- 3x3 conv, f-part shared between both relations; 1 pixel/thread ----
    const int ly = tid >> 4, lx = tid & 15;
    const int hc = (ly + 1) * HST + (lx + 1);

    float accf[10], acc0[10], acc1[10];
    #pragma unroll
    for (int c = 0; c < 10; c++) { accf[c] = 0.f; acc0[c] = 0.f; acc1[c] = 0.f; }

    #pragma unroll 1  // keep 9-tap loop rolled (icache); ci/c fully unrolled
    for (int tap = 0; tap < 9; tap++) {
        const int hi = hc + (tap / 3 - 1) * HST + (tap - (tap / 3) * 3 - 1);
        #pragma unroll
        for (int ci = 0; ci < 10; ci++) {
            const float4 v = sIn[ci][hi];                 // one ds_read_b128
            const float* __restrict__ wp = ws + WOFF_W3 + (tap * 10 + ci) * 20;  // uniform -> s_load
            #pragma unroll
            for (int c = 0; c < 10; c++) {
                accf[c] += wp[c]      * v.x;
                acc0[c] += wp[10 + c] * v.y;
                acc1[c] += wp[10 + c] * v.z;
            }
        }
    }

    // ---- BN(folded) + ReLU + sum; ConvGRU (1x1) ----
    float ch[10], fc[10], attv = 0.f;
    #pragma unroll
    for (int c = 0; c < 10; c++) {
        const float4 cv = sIn[c][hc];
        fc[c] = cv.x;
        if (c == 0) attv = cv.w;
        const float bi = ws[WOFF_BI + c];
        ch[c] = fmaxf(accf[c] + acc0[c] + bi, 0.f) + fmaxf(accf[c] + acc1[c] + bi, 0.f);
    }

    float g[20];
    #pragma unroll
    for (int o = 0; o < 20; o++) g[o] = ws[WOFF_GB + o];
    #pragma unroll
    for (int i = 0; i < 10; i++) {
        #pragma unroll
        for (int o = 0; o < 20; o++)
            g[o] += ch[i] * ws[WOFF_GW + i * 20 + o] + fc[i] * ws[WOFF_GW + (10 + i) * 20 + o];
    }
    float cd[10];
    #pragma unroll
    for (int c = 0; c < 10; c++) cd[c] = ws[WOFF_CB + c];
    #pragma unroll
    for (int i = 0; i < 10; i++) {
        const float rf = sigm(g[i]) * fc[i];   // reset * f
        #pragma unroll
        for (int c = 0; c < 10; c++)
            cd[c] += ch[i] * ws[WOFF_CW + i * 10 + c] + rf * ws[WOFF_CW + (10 + i) * 10 + c];
    }

    const int gy = by * TS + ly, gx = bx * TS + lx;
    #pragma unroll
    for (int c = 0; c < 10; c++) {
        const float u = sigm(g[10 + c]);       // update gate
        out_f[((b * C_ + c) * H_ + gy) * W_ + gx] = (1.f - u) * fc[c] + u * tanh_(cd[c]);
    }
    out_att[(b * H_ + gy) * W_ + gx] = attv;
}

extern "C" void kernel_launch(void* const* d_in, const int* in_sizes, int n_in,
                              void* d_out, int out_size, void* d_ws, size_t ws_size,
                              hipStream_t stream) {
    (void)in_sizes; (void)n_in; (void)ws_size; (void)out_size;
    const float* f   = (const float*)d_in[0];
    const float* h0  = (const float*)d_in[1];
    const float* h1  = (const float*)d_in[2];
    // d_in[3] = p_nodes, d_in[4] = xf: unused by the reference -> never read
    const float* aw  = (const float*)d_in[5];
    const float* ab  = (const float*)d_in[6];
    const float* rw  = (const float*)d_in[7];
    const float* gam = (const float*)d_in[8];
    const float* bet = (const float*)d_in[9];
    const float* mea = (const float*)d_in[10];
    const float* var = (const float*)d_in[11];
    const float* gw  = (const float*)d_in[12];
    const float* gb  = (const float*)d_in[13];
    const float* cw  = (const float*)d_in[14];
    const float* cb  = (const float*)d_in[15];

    float* wsf     = (float*)d_ws;
    float* out_f   = (float*)d_out;
    float* out_att = out_f + (B_ * C_ * H_ * W_);

    prep_kernel<<<1, 256, 0, stream>>>(aw, ab, rw, gam, bet, mea, var, gw, gb, cw, cb, wsf);

    dim3 grid(W_ / TS, H_ / TS, B_);
    fused_graph_kernel<<<grid, dim3(NTHREADS), 0, stream>>>(f, h0, h1, wsf, out_f, out_att);
}